// Round 9
// baseline (2876.987 us; speedup 1.0000x reference)
//
#include <hip/hip_runtime.h>
#include <hip/hip_bf16.h>

typedef __bf16 bfx8 __attribute__((ext_vector_type(8)));
typedef __bf16 bfx4 __attribute__((ext_vector_type(4)));
typedef float f32x4 __attribute__((ext_vector_type(4)));

#define MFMA __builtin_amdgcn_mfma_f32_16x16x32_bf16

// Dims: S=32 T=32 B=512 H=1024 E=256 A=1024 VS=64 VT=70 START=1
// f32 in/out; MFMA on bf16. All weights pre-swizzled fragment-major
// (16x32 fragment = 64 lanes x 16B contiguous -> coalesced 1KB wave loads).
// gru_step v4: j=32 x m=64 blocks (halved per-CU W stream vs j=64), 8 waves,
// sequential gh->gi phases sharing one 128KB LDS A-buffer (A2 in 2 chunks).

__device__ __attribute__((aligned(256))) float  g_h[512 * 1024];
__device__ __attribute__((aligned(256))) float  g_hpart[512 * 1024];
__device__ __attribute__((aligned(256))) __bf16 g_hb[2][512 * 1024];
__device__ __attribute__((aligned(256))) __bf16 g_Adec[512 * 1280];
__device__ __attribute__((aligned(256))) __bf16 g_enc_ops[(size_t)32 * 512 * 1024];
__device__ __attribute__((aligned(256))) __bf16 g_enc_part[(size_t)32 * 512 * 1024];
__device__ __attribute__((aligned(256))) __bf16 g_sWhhe[(size_t)3072 * 1024];   // fragment-major
__device__ __attribute__((aligned(256))) __bf16 g_sWihe[(size_t)3072 * 256];
__device__ __attribute__((aligned(256))) __bf16 g_sWhhd[(size_t)3072 * 1024];
__device__ __attribute__((aligned(256))) __bf16 g_sWihd[(size_t)3072 * 1280];
__device__ __attribute__((aligned(256))) __bf16 g_sWattnA[(size_t)1024 * 1024];
__device__ __attribute__((aligned(256))) __bf16 g_sWattnB[(size_t)1024 * 1024];
__device__ __attribute__((aligned(256))) __bf16 g_sWout[(size_t)128 * 1024];
__device__ __attribute__((aligned(256))) __bf16 g_embs[64 * 256];
__device__ __attribute__((aligned(256))) __bf16 g_embt[70 * 256];

__device__ __forceinline__ float fast_tanh(float x) {
    float cx = fminf(fmaxf(x, -15.f), 15.f);
    float e = __expf(-2.f * cx);
    return (1.f - e) / (1.f + e);
}

// ---------------------------------------------------------------------------
__global__ void k_cvt(const float* __restrict__ src, __bf16* __restrict__ dst,
                      int n4)
{
    int i = blockIdx.x * 256 + threadIdx.x;
    if (i >= n4) return;
    float4 v = ((const float4*)src)[i];
    __bf16 o[4] = {(__bf16)v.x, (__bf16)v.y, (__bf16)v.z, (__bf16)v.w};
    *(ushort2*)(dst + 4 * i) = *(ushort2*)o;
    *(ushort2*)(dst + 4 * i + 2) = *(ushort2*)(o + 2);
}

// Row-major f32 W[R][K] -> fragment-major bf16.
__global__ void swz_rm(const float* __restrict__ W, __bf16* __restrict__ out,
                       int nK, int total)
{
    int gid = blockIdx.x * 256 + threadIdx.x;
    if (gid >= total) return;
    int F = gid >> 6, L = gid & 63;
    int t = F / nK, c = F - t * nK;
    int K = nK * 32;
    const float* s = W + (size_t)(t * 16 + (L & 15)) * K + c * 32 + (L >> 4) * 8;
    __bf16 o[8];
#pragma unroll
    for (int u = 0; u < 8; u++) o[u] = (__bf16)s[u];
    *(uint4*)(out + (size_t)gid * 8) = *(uint4*)o;
}

// Column-gather: logical W'[n][k] = W[k*ldsrc + n]; n>=nguard -> 0.
__global__ void swz_cm(const float* __restrict__ W, __bf16* __restrict__ out,
                       int nK, int ldsrc, int nguard, int total)
{
    int gid = blockIdx.x * 256 + threadIdx.x;
    if (gid >= total) return;
    int F = gid >> 6, L = gid & 63;
    int t = F / nK, c = F - t * nK;
    int n = t * 16 + (L & 15);
    int k = c * 32 + (L >> 4) * 8;
    __bf16 o[8];
#pragma unroll
    for (int u = 0; u < 8; u++)
        o[u] = (n < nguard) ? (__bf16)W[(size_t)(k + u) * ldsrc + n] : (__bf16)0.f;
    *(uint4*)(out + (size_t)gid * 8) = *(uint4*)o;
}

__global__ void k_init(float* __restrict__ out)
{
    int idx = blockIdx.x * 256 + threadIdx.x;
    if (idx < 512 * 1024) { g_h[idx] = 0.f; g_hb[0][idx] = (__bf16)0.f; }
    if (idx < 512 * 70) out[idx] = (idx % 70 == 1) ? 1.f : 0.f;
}

// ---------------------------------------------------------------------------
// Fused GRU step v4. grid (32 j-tiles, 8 m-tiles) = 256 blocks, 512 thr.
// Block: 64 batch rows x 32 j-cols x 3 gates. Wave w: jsub = w&1 (16 j),
// mg = w>>1 (16 rows). Phase A: gh = hb_in @ W1^T (K=1024); phase B:
// gi = A2 @ W2^T (K=nK2*32), A2 staged in 2 chunks reusing the A1 buffer.
// Both accumulator sets live in the same wave -> direct GRU epilogue.
// W fragment-major coalesced; same-j waves' redundant W reads hit L1.
// ---------------------------------------------------------------------------
__global__ __launch_bounds__(512, 1) void gru_step(
    const __bf16* __restrict__ hb_in, __bf16* __restrict__ hb_out,
    const __bf16* __restrict__ sW1, const float* __restrict__ b1,
    const __bf16* __restrict__ sW2, const float* __restrict__ b2,
    int nK2, const int* __restrict__ src_t, int enc_t)
{
    __shared__ __bf16 sBuf[65536];   // 128 KB, reused A1 then A2 chunks
    const int tid = threadIdx.x;
    const int w = tid >> 6, lane = tid & 63;
    const int r15 = lane & 15, q = lane >> 4;
    const int jsub = w & 1, mg = w >> 1;
    const int j0 = blockIdx.x * 32, m0 = blockIdx.y * 64;
    const int xk = r15 & 7;
    const int t1 = blockIdx.x * 2 + jsub;

    // ---- stage A1: 64 rows x 128 units, xor-swizzled ----
#pragma unroll
    for (int i = 0; i < 16; i++) {
        int lin = tid + i * 512;
        int r = lin >> 7, U = lin & 127;
        uint4 v = *(const uint4*)(hb_in + (size_t)(m0 + r) * 1024 + U * 8);
        *(uint4*)(sBuf + (r * 128 + (U ^ (r & 7))) * 8) = v;
    }
    __syncthreads();

    f32x4 agh[3], agi[3];
#pragma unroll
    for (int s = 0; s < 3; s++) {
        agh[s] = (f32x4){0.f, 0.f, 0.f, 0.f};
        agi[s] = (f32x4){0.f, 0.f, 0.f, 0.f};
    }

    // ---- phase A: gh (32 k-frags) ----
    {
        const __bf16* wp0 = sW1 + ((size_t)t1 * 32) * 512 + lane * 8;
        const __bf16* wp1 = sW1 + ((size_t)(t1 + 64) * 32) * 512 + lane * 8;
        const __bf16* wp2 = sW1 + ((size_t)(t1 + 128) * 32) * 512 + lane * 8;
        const int ar = (mg * 16 + r15) * 128;
#pragma unroll 4
        for (int c = 0; c < 32; c++) {
            bfx8 a  = *(const bfx8*)(sBuf + (ar + ((c * 4 + q) ^ xk)) * 8);
            bfx8 w0 = *(const bfx8*)(wp0 + c * 512);
            bfx8 w1 = *(const bfx8*)(wp1 + c * 512);
            bfx8 w2 = *(const bfx8*)(wp2 + c * 512);
            agh[0] = MFMA(a, w0, agh[0], 0, 0, 0);
            agh[1] = MFMA(a, w1, agh[1], 0, 0, 0);
            agh[2] = MFMA(a, w2, agh[2], 0, 0, 0);
        }
    }

    // ---- phase B: gi, A2 in 2 chunks of uc units/row ----
    const int uc = nK2 * 2;          // units per row per chunk (dec 80, enc 16)
    const int hk = nK2 >> 1;         // k-frags per chunk
    const __bf16* wq0 = sW2 + ((size_t)t1 * nK2) * 512 + lane * 8;
    const __bf16* wq1 = sW2 + ((size_t)(t1 + 64) * nK2) * 512 + lane * 8;
    const __bf16* wq2 = sW2 + ((size_t)(t1 + 128) * nK2) * 512 + lane * 8;
    for (int ch = 0; ch < 2; ch++) {
        __syncthreads();  // protect previous contents
        if (src_t) {      // encoder: emb gather
            for (int lin = tid; lin < 64 * 16; lin += 512) {
                int r = lin >> 4, U = lin & 15;
                int sv = src_t[m0 + r];
                sv = (sv < 0) ? 0 : (sv > 63 ? 63 : sv);
                uint4 v = *(const uint4*)(g_embs + sv * 256 + (ch * 16 + U) * 8);
                *(uint4*)(sBuf + (r * 16 + (U ^ (r & 7))) * 8) = v;
            }
        } else {          // decoder: Adec
            for (int lin = tid; lin < 64 * 80; lin += 512) {
                int r = lin / 80, U = lin - r * 80;
                uint4 v = *(const uint4*)(g_Adec + (size_t)(m0 + r) * 1280 +
                                          (ch * 80 + U) * 8);
                *(uint4*)(sBuf + (r * 80 + (U ^ (r & 7))) * 8) = v;
            }
        }
        __syncthreads();
        const int ar = (mg * 16 + r15) * uc;
#pragma unroll 4
        for (int cl = 0; cl < hk; cl++) {
            int c = ch * hk + cl;
            bfx8 a  = *(const bfx8*)(sBuf + (ar + ((cl * 4 + q) ^ xk)) * 8);
            bfx8 w0 = *(const bfx8*)(wq0 + c * 512);
            bfx8 w1 = *(const bfx8*)(wq1 + c * 512);
            bfx8 w2 = *(const bfx8*)(wq2 + c * 512);
            agi[0] = MFMA(a, w0, agi[0], 0, 0, 0);
            agi[1] = MFMA(a, w1, agi[1], 0, 0, 0);
            agi[2] = MFMA(a, w2, agi[2], 0, 0, 0);
        }
    }

    // ---- GRU epilogue (every wave owns its (jsub, mg) tile) ----
    const int jj = j0 + jsub * 16 + r15;
    const float bb1[3] = {b1[jj], b1[1024 + jj], b1[2048 + jj]};
    const float bb2[3] = {b2[jj], b2[1024 + jj], b2[2048 + jj]};
#pragma unroll
    for (int reg = 0; reg < 4; reg++) {
        int b_ = m0 + mg * 16 + q * 4 + reg;
        float gh0 = agh[0][reg] + bb1[0];
        float gh1 = agh[1][reg] + bb1[1];
        float gh2 = agh[2][reg] + bb1[2];
        float gi0 = agi[0][reg] + bb2[0];
        float gi1 = agi[1][reg] + bb2[1];
        float gi2 = agi[2][reg] + bb2[2];
        float r = 1.f / (1.f + __expf(-(gi0 + gh0)));
        float z = 1.f / (1.f + __expf(-(gi1 + gh1)));
        float n = fast_tanh(gi2 + r * gh2);
        size_t off = (size_t)b_ * 1024 + jj;
        float hv = (1.f - z) * n + z * g_h[off];
        g_h[off] = hv;
        hb_out[off] = (__bf16)hv;
        if (enc_t >= 0) g_enc_ops[(size_t)enc_t * 524288 + off] = (__bf16)hv;
    }
}

// ---------------------------------------------------------------------------
// enc_part = enc_ops @ W_attn[H:2H]^T, bf16 out. grid (16 n-tiles, 512 m).
// Stage 32 A-rows in LDS; stream sWattnB fragment-major; barrier-free K-loop.
// ---------------------------------------------------------------------------
__global__ __launch_bounds__(256) void k_ep()
{
    __shared__ __bf16 sA[32 * 1024];
    const int tid = threadIdx.x;
    const int w = tid >> 6, lane = tid & 63;
    const int r15 = lane & 15, q = lane >> 4;
    const int bx = blockIdx.x, m0 = blockIdx.y * 32;

#pragma unroll
    for (int i = 0; i < 16; i++) {
        int lin = tid + i * 256;
        int r = lin >> 7, U = lin & 127;
        uint4 v = *(const uint4*)(g_enc_ops + (size_t)(m0 + r) * 1024 + U * 8);
        *(uint4*)(sA + (r * 128 + (U ^ (r & 7))) * 8) = v;
    }
    __syncthreads();

    const int t = bx * 4 + w;
    const __bf16* wp = g_sWattnB + ((size_t)t * 32) * 512 + lane * 8;
    const int xk = r15 & 7;
    const int ar0 = r15 * 128, ar1 = (16 + r15) * 128;

    f32x4 acc[2];
    acc[0] = (f32x4){0.f, 0.f, 0.f, 0.f};
    acc[1] = (f32x4){0.f, 0.f, 0.f, 0.f};
#pragma unroll 4
    for (int c = 0; c < 32; c++) {
        int us = (c * 4 + q) ^ xk;
        bfx8 a0 = *(const bfx8*)(sA + (ar0 + us) * 8);
        bfx8 a1 = *(const bfx8*)(sA + (ar1 + us) * 8);
        bfx8 wv = *(const bfx8*)(wp + c * 512);
        acc[0] = MFMA(a0, wv, acc[0], 0, 0, 0);
        acc[1] = MFMA(a1, wv, acc[1], 0, 0, 0);
    }
    int n = bx * 64 + w * 16 + r15;
#pragma unroll
    for (int mf = 0; mf < 2; mf++)
#pragma unroll
        for (int reg = 0; reg < 4; reg++)
            g_enc_part[(size_t)(m0 + mf * 16 + q * 4 + reg) * 1024 + n] =
                (__bf16)acc[mf][reg];
}

// ---------------------------------------------------------------------------
// Fused [hpart | logits] from h (bf16). grid (18, 16). bx<16: hpart col-tile;
// bx 16..17: logits (guard 70) -> out row lrow (skipped if lrow<0).
// ---------------------------------------------------------------------------
__global__ __launch_bounds__(256) void k_hl(
    const __bf16* __restrict__ src, const float* __restrict__ battn,
    const float* __restrict__ bout, int lrow, float* __restrict__ outp)
{
    __shared__ __bf16 sA[32 * 1024];
    const int tid = threadIdx.x;
    const int w = tid >> 6, lane = tid & 63;
    const int r15 = lane & 15, q = lane >> 4;
    const int bx = blockIdx.x, m0 = blockIdx.y * 32;

#pragma unroll
    for (int i = 0; i < 16; i++) {
        int lin = tid + i * 256;
        int r = lin >> 7, U = lin & 127;
        uint4 v = *(const uint4*)(src + (size_t)(m0 + r) * 1024 + U * 8);
        *(uint4*)(sA + (r * 128 + (U ^ (r & 7))) * 8) = v;
    }
    __syncthreads();

    const __bf16* sW;
    int n;
    if (bx < 16) {
        sW = g_sWattnA;
        n = bx * 64 + w * 16 + r15;
    } else {
        if (lrow < 0) return;
        sW = g_sWout;
        n = (bx - 16) * 64 + w * 16 + r15;
    }
    const size_t tb = (size_t)((bx < 16 ? bx : bx - 16) * 4 + w);
    const __bf16* wp = sW + (tb * 32) * 512 + lane * 8;
    const int xk = r15 & 7;
    const int ar0 = r15 * 1024, ar1 = (16 + r15) * 1024;

    f32x4 acc[2];
    acc[0] = (f32x4){0.f, 0.f, 0.f, 0.f};
    acc[1] = (f32x4){0.f, 0.f, 0.f, 0.f};
#pragma unroll 4
    for (int c = 0; c < 32; c++) {
        int us = ((c * 4 + q) ^ xk) * 8;
        bfx8 a0 = *(const bfx8*)(sA + ar0 + us);
        bfx8 a1 = *(const bfx8*)(sA + ar1 + us);
        bfx8 wv = *(const bfx8*)(wp + c * 512);
        acc[0] = MFMA(a0, wv, acc[0], 0, 0, 0);
        acc[1] = MFMA(a1, wv, acc[1], 0, 0, 0);
    }

    if (bx < 16) {
        float bv = battn[n];
#pragma unroll
        for (int ms = 0; ms < 2; ms++)
#pragma unroll
            for (int reg = 0; reg < 4; reg++)
                g_hpart[(size_t)(m0 + ms * 16 + q * 4 + reg) * 1024 + n] =
                    acc[ms][reg] + bv;
    } else if (n < 70) {
        float bv = bout[n];
#pragma unroll
        for (int ms = 0; ms < 2; ms++)
#pragma unroll
            for (int reg = 0; reg < 4; reg++)
                outp[(size_t)lrow * 35840 +
                     (size_t)(m0 + ms * 16 + q * 4 + reg) * 70 + n] =
                    acc[ms][reg] + bv;
    }
}

// ---------------------------------------------------------------------------
// Attention step: x-select + embed + scores + softmax + alpha out + ctx.
// One block per batch b.
// ---------------------------------------------------------------------------
__global__ __launch_bounds__(256) void k_attn(
    int j, const int* __restrict__ target, const int* __restrict__ tf,
    const float* __restrict__ v_attn, float* __restrict__ out)
{
    const int b = blockIdx.x, tid = threadIdx.x;
    const int lane = tid & 63, wave = tid >> 6;
    __shared__ float sc[32], sal[32];
    __shared__ int sx;
    if (wave == 0) {
        int xv;
        if (j == 0) xv = target[b];
        else if (*tf) xv = target[j * 512 + b];
        else {
            const float* row = out + (size_t)j * 35840 + b * 70;
            float bv = row[lane]; int bi = lane;
            if (lane < 6) {
                float v2 = row[lane + 64];
                if (v2 > bv) { bv = v2; bi = lane + 64; }
            }
#pragma unroll
            for (int off = 32; off; off >>= 1) {
                float ov = __shfl_down(bv, off);
                int   oi = __shfl_down(bi, off);
                if (ov > bv || (ov == bv && oi < bi)) { bv = ov; bi = oi; }
            }
            xv = bi;
        }
        if (lane == 0) sx = (xv < 0) ? 0 : (xv > 69 ? 69 : xv);
    }
    float hpv[16], vsv[16];
    {
        const float* hp = g_hpart + (size_t)b * 1024;
#pragma unroll
        for (int u = 0; u < 8; u++) {
            hpv[u]     = hp[lane * 8 + u];
            hpv[8 + u] = hp[512 + lane * 8 + u];
            vsv[u]     = v_attn[lane * 8 + u];
            vsv[8 + u] = v_attn[512 + lane * 8 + u];
        }
    }
    __syncthreads();
    g_Adec[(size_t)b * 1280 + 1024 + tid] = g_embt[sx * 256 + tid];
    for (int s = wave * 8; s < wave * 8 + 8; s++) {
        const __bf16* ep = g_enc_part + ((size_t)s * 512 + b) * 1024;
        bfx8 e0 = *(const bfx8*)(ep + lane * 8);
        bfx8 e1 = *(const bfx8*)(ep + 512 + lane * 8);
        float part = 0.f;
#pragma unroll
        for (int u = 0; u < 8; u++) {
            part += vsv[u]     * fast_tanh((float)e0[u] + hpv[u]);
            part += vsv[8 + u] * fast_tanh((float)e1[u] + hpv[8 + u]);
        }
#pragma unroll
        for (int off = 32; off; off >>= 1) part += __shfl_down(part, off);
        if (lane == 0) sc[s] = part;
    }
    __syncthreads();
    float mx = sc[0];
#pragma unroll
    for (int s = 1; s < 32; s++) mx = fmaxf(mx, sc[s]);
    float den = 0.f;
#pragma unroll
    for (int s = 0; s < 32; s++) den += __expf(sc[s] - mx);
    float rden = 1.f / den;
    if (tid < 32) {
        float al = __expf(sc[tid] - mx) * rden;
        sal[tid] = al;
        out[1146880 + (size_t)j * 16384 + b * 32 + tid] = al;
    }
    __syncthreads();
    float c0 = 0, c1 = 0, c2 = 0, c3 = 0;
    const __bf16* eo = g_enc_ops + (size_t)b * 1024 + tid * 4;
#pragma unroll 4
    for (int s = 0; s < 32; s++) {
        bfx4 e = *(const bfx4*)(eo + (size_t)s * 524288);
        float al = sal[s];
        c0 += al * (float)e[0]; c1 += al * (float)e[1];
        c2 += al * (float)e[2]; c3 += al * (float)e[3];
    }
    bfx4 o = {(__bf16)c0, (__bf16)c1, (__bf16)c2, (__bf16)c3};
    *(bfx4*)(&g_Adec[(size_t)b * 1280 + tid * 4]) = o;
}

// ---------------------------------------------------------------------------
extern "C" void kernel_launch(void* const* d_in, const int* in_sizes, int n_in,
                              void* d_out, int out_size, void* d_ws, size_t ws_size,
                              hipStream_t stream)
{
    const int*   source   = (const int*)d_in[0];
    const int*   target   = (const int*)d_in[1];
    const int*   tf       = (const int*)d_in[2];
    const float* emb_src  = (const float*)d_in[3];
    const float* W_ih_enc = (const float*)d_in[4];
    const float* W_hh_enc = (const float*)d_in[5];
    const float* b_ih_enc = (const float*)d_in[6];
    const float* b_hh_enc = (const float*)d_in[7];
    const float* emb_tgt  = (const float*)d_in[8];
    const float* W_attn   = (const float*)d_in[9];
    const float* b_attn   = (const float*)d_in[10];
    const float* v_attn   = (const float*)d_in[11];
    const float* W_ih_dec = (const float*)d_in[12];
    const float* W_hh_dec = (const float*)d_in[13];
    const float* b_ih_dec = (const float*)d_in[14];
    const float* b_hh_dec = (const float*)d_in[15];
    const float* W_out    = (const float*)d_in[16];
    const float* b_out    = (const float*)d_in[17];
    float* out = (float*)d_out;

    void *p_hb, *p_sWhhe, *p_sWihe, *p_sWhhd, *p_sWihd, *p_sWattnA, *p_sWattnB,
         *p_sWout, *p_embs, *p_embt;
    hipGetSymbolAddress(&p_hb,      HIP_SYMBOL(g_hb));
    hipGetSymbolAddress(&p_sWhhe,   HIP_SYMBOL(g_sWhhe));
    hipGetSymbolAddress(&p_sWihe,   HIP_SYMBOL(g_sWihe));
    hipGetSymbolAddress(&p_sWhhd,   HIP_SYMBOL(g_sWhhd));
    hipGetSymbolAddress(&p_sWihd,   HIP_SYMBOL(g_sWihd));
    hipGetSymbolAddress(&p_sWattnA, HIP_SYMBOL(g_sWattnA));
    hipGetSymbolAddress(&p_sWattnB, HIP_SYMBOL(g_sWattnB));
    hipGetSymbolAddress(&p_sWout,   HIP_SYMBOL(g_sWout));
    hipGetSymbolAddress(&p_embs,    HIP_SYMBOL(g_embs));
    hipGetSymbolAddress(&p_embt,    HIP_SYMBOL(g_embt));
    __bf16* hb0 = (__bf16*)p_hb;
    __bf16* hb1 = hb0 + 512 * 1024;

    // ---- one-time setup ----
    k_cvt<<<16, 256, 0, stream>>>(emb_src, (__bf16*)p_embs, 64 * 256 / 4);
    k_cvt<<<18, 256, 0, stream>>>(emb_tgt, (__bf16*)p_embt, 70 * 256 / 4);
    swz_rm<<<1536, 256, 0, stream>>>(W_hh_enc, (__bf16*)p_sWhhe, 32, 393216);
    swz_rm<<<384,  256, 0, stream>>>(W_ih_enc, (__bf16*)p_sWihe, 8,  98304);
    swz_rm<<<1536, 256, 0, stream>>>(W_hh_dec, (__bf16*)p_sWhhd, 32, 393216);
    swz_rm<<<1920, 256, 0, stream>>>(W_ih_dec, (__bf16*)p_sWihd, 40, 491520);
    swz_cm<<<512,  256, 0, stream>>>(W_attn, (__bf16*)p_sWattnA, 32, 1024, 1024, 131072);
    swz_cm<<<512,  256, 0, stream>>>(W_attn + (size_t)1024 * 1024,
                                     (__bf16*)p_sWattnB, 32, 1024, 1024, 131072);
    swz_cm<<<64,   256, 0, stream>>>(W_out, (__bf16*)p_sWout, 32, 70, 70, 16384);
    k_init<<<2048, 256, 0, stream>>>(out);

    // -------- Encoder: 32 steps --------
    for (int t = 0; t < 32; t++) {
        __bf16* hin  = (t & 1) ? hb1 : hb0;
        __bf16* hout = (t & 1) ? hb0 : hb1;
        gru_step<<<dim3(32, 8), 512, 0, stream>>>(
            hin, hout, (__bf16*)p_sWhhe, b_hh_enc,
            (__bf16*)p_sWihe, b_ih_enc, 8, source + t * 512, t);
    }
    // h_enc lands in hb0

    // enc_part = enc_ops @ W_attn[H:2H]^T
    k_ep<<<dim3(16, 512), 256, 0, stream>>>();

    // hpart for step 0
    k_hl<<<dim3(18, 16), 256, 0, stream>>>(hb0, b_attn, b_out, -1, out);

    // -------- Decoder: 31 steps --------
    for (int j = 0; j < 31; j++) {
        __bf16* hin  = (j & 1) ? hb1 : hb0;
        __bf16* hout = (j & 1) ? hb0 : hb1;
        k_attn<<<512, 256, 0, stream>>>(j, target, tf, v_attn, out);
        gru_step<<<dim3(32, 8), 512, 0, stream>>>(
            hin, hout, (__bf16*)p_sWhhd, b_hh_dec,
            (__bf16*)p_sWihd, b_ih_dec, 40, nullptr, -1);
        k_hl<<<dim3(18, 16), 256, 0, stream>>>(hout, b_attn, b_out, j + 1, out);
    }
}

// Round 10
// 2795.084 us; speedup vs baseline: 1.0293x; 1.0293x over previous
//
#include <hip/hip_runtime.h>
#include <hip/hip_bf16.h>

typedef __bf16 bfx8 __attribute__((ext_vector_type(8)));
typedef __bf16 bfx4 __attribute__((ext_vector_type(4)));
typedef float f32x4 __attribute__((ext_vector_type(4)));

#define MFMA __builtin_amdgcn_mfma_f32_16x16x32_bf16

// Dims: S=32 T=32 B=512 H=1024 E=256 A=1024 VS=64 VT=70 START=1
// f32 in/out; MFMA on bf16. Weights fragment-major (16x32 frag = 64 lanes x
// 16B contiguous -> coalesced 1KB wave loads). gru_step v5: j=64 x m=32,
// 512 thr, 8 waves all-compute, 40KB chunked LDS -> 2 blocks/CU.

__device__ __attribute__((aligned(256))) float  g_h[512 * 1024];
__device__ __attribute__((aligned(256))) float  g_hpart[512 * 1024];
__device__ __attribute__((aligned(256))) __bf16 g_hb[2][512 * 1024];
__device__ __attribute__((aligned(256))) __bf16 g_Adec[512 * 1280];
__device__ __attribute__((aligned(256))) __bf16 g_enc_ops[(size_t)32 * 512 * 1024];
__device__ __attribute__((aligned(256))) __bf16 g_enc_part[(size_t)32 * 512 * 1024];
__device__ __attribute__((aligned(256))) __bf16 g_sWhhe[(size_t)3072 * 1024];   // fragment-major
__device__ __attribute__((aligned(256))) __bf16 g_sWihe[(size_t)3072 * 256];
__device__ __attribute__((aligned(256))) __bf16 g_sWhhd[(size_t)3072 * 1024];
__device__ __attribute__((aligned(256))) __bf16 g_sWihd[(size_t)3072 * 1280];
__device__ __attribute__((aligned(256))) __bf16 g_sWattnA[(size_t)1024 * 1024];
__device__ __attribute__((aligned(256))) __bf16 g_sWattnB[(size_t)1024 * 1024];
__device__ __attribute__((aligned(256))) __bf16 g_sWout[(size_t)128 * 1024];
__device__ __attribute__((aligned(256))) __bf16 g_embs[64 * 256];
__device__ __attribute__((aligned(256))) __bf16 g_embt[70 * 256];

__device__ __forceinline__ float fast_tanh(float x) {
    float cx = fminf(fmaxf(x, -15.f), 15.f);
    float e = __expf(-2.f * cx);
    return (1.f - e) / (1.f + e);
}

// ---------------------------------------------------------------------------
__global__ void k_cvt(const float* __restrict__ src, __bf16* __restrict__ dst,
                      int n4)
{
    int i = blockIdx.x * 256 + threadIdx.x;
    if (i >= n4) return;
    float4 v = ((const float4*)src)[i];
    __bf16 o[4] = {(__bf16)v.x, (__bf16)v.y, (__bf16)v.z, (__bf16)v.w};
    *(ushort2*)(dst + 4 * i) = *(ushort2*)o;
    *(ushort2*)(dst + 4 * i + 2) = *(ushort2*)(o + 2);
}

// Row-major f32 W[R][K] -> fragment-major bf16.
__global__ void swz_rm(const float* __restrict__ W, __bf16* __restrict__ out,
                       int nK, int total)
{
    int gid = blockIdx.x * 256 + threadIdx.x;
    if (gid >= total) return;
    int F = gid >> 6, L = gid & 63;
    int t = F / nK, c = F - t * nK;
    int K = nK * 32;
    const float* s = W + (size_t)(t * 16 + (L & 15)) * K + c * 32 + (L >> 4) * 8;
    __bf16 o[8];
#pragma unroll
    for (int u = 0; u < 8; u++) o[u] = (__bf16)s[u];
    *(uint4*)(out + (size_t)gid * 8) = *(uint4*)o;
}

// Column-gather: logical W'[n][k] = W[k*ldsrc + n]; n>=nguard -> 0.
__global__ void swz_cm(const float* __restrict__ W, __bf16* __restrict__ out,
                       int nK, int ldsrc, int nguard, int total)
{
    int gid = blockIdx.x * 256 + threadIdx.x;
    if (gid >= total) return;
    int F = gid >> 6, L = gid & 63;
    int t = F / nK, c = F - t * nK;
    int n = t * 16 + (L & 15);
    int k = c * 32 + (L >> 4) * 8;
    __bf16 o[8];
#pragma unroll
    for (int u = 0; u < 8; u++)
        o[u] = (n < nguard) ? (__bf16)W[(size_t)(k + u) * ldsrc + n] : (__bf16)0.f;
    *(uint4*)(out + (size_t)gid * 8) = *(uint4*)o;
}

__global__ void k_init(float* __restrict__ out)
{
    int idx = blockIdx.x * 256 + threadIdx.x;
    if (idx < 512 * 1024) { g_h[idx] = 0.f; g_hb[0][idx] = (__bf16)0.f; }
    if (idx < 512 * 70) out[idx] = (idx % 70 == 1) ? 1.f : 0.f;
}

// ---------------------------------------------------------------------------
// Fused GRU step v5. grid (16 j-tiles, 16 m-tiles) = 256 blocks, 512 thr,
// __launch_bounds__(512,4) -> 2 blocks/CU (16 waves/CU). Block: 32 rows x
// 64 j x 3 gates. Wave w: jsub = w&3 (16 j), mg = w>>2 (16 rows); owns both
// gh and gi accumulators -> direct epilogue, no handoff.
// LDS: one 40KB buffer; A1 staged in 2x32KB K-chunks, A2 in 2x40KB (dec) or
// 1x16KB (enc, emb gather). K-loops barrier-free between chunk syncs.
// ---------------------------------------------------------------------------
__global__ __launch_bounds__(512, 4) void gru_step(
    const __bf16* __restrict__ hb_in, __bf16* __restrict__ hb_out,
    const __bf16* __restrict__ sW1, const float* __restrict__ b1,
    const __bf16* __restrict__ sW2, const float* __restrict__ b2,
    int nK2, const int* __restrict__ src_t, int enc_t)
{
    __shared__ __bf16 sBuf[20480];   // 40 KB
    const int tid = threadIdx.x;
    const int w = tid >> 6, lane = tid & 63;
    const int r15 = lane & 15, q = lane >> 4;
    const int jsub = w & 3, mg = w >> 2;
    const int j0 = blockIdx.x * 64, m0 = blockIdx.y * 32;
    const int xk = r15 & 7;
    const int t1 = blockIdx.x * 4 + jsub;

    f32x4 agh[3], agi[3];
#pragma unroll
    for (int s = 0; s < 3; s++) {
        agh[s] = (f32x4){0.f, 0.f, 0.f, 0.f};
        agi[s] = (f32x4){0.f, 0.f, 0.f, 0.f};
    }

    // ---- phase A: gh = hb_in @ W1^T (K=1024), 2 chunks of 512 ----
    {
        const __bf16* wp0 = sW1 + ((size_t)t1 * 32) * 512 + lane * 8;
        const __bf16* wp1 = sW1 + ((size_t)(t1 + 64) * 32) * 512 + lane * 8;
        const __bf16* wp2 = sW1 + ((size_t)(t1 + 128) * 32) * 512 + lane * 8;
        const int ar = (mg * 16 + r15) * 64;
        for (int ch = 0; ch < 2; ch++) {
            if (ch) __syncthreads();
            // stage 32 rows x 64 units (32 KB)
#pragma unroll
            for (int i = 0; i < 4; i++) {
                int lin = tid + i * 512;
                int r = lin >> 6, U = lin & 63;
                uint4 v = *(const uint4*)(hb_in + (size_t)(m0 + r) * 1024 +
                                          ch * 512 + U * 8);
                *(uint4*)(sBuf + (r * 64 + (U ^ (r & 7))) * 8) = v;
            }
            __syncthreads();
#pragma unroll 4
            for (int cl = 0; cl < 16; cl++) {
                int c = ch * 16 + cl;
                bfx8 a  = *(const bfx8*)(sBuf + (ar + ((cl * 4 + q) ^ xk)) * 8);
                bfx8 w0 = *(const bfx8*)(wp0 + c * 512);
                bfx8 w1 = *(const bfx8*)(wp1 + c * 512);
                bfx8 w2 = *(const bfx8*)(wp2 + c * 512);
                agh[0] = MFMA(a, w0, agh[0], 0, 0, 0);
                agh[1] = MFMA(a, w1, agh[1], 0, 0, 0);
                agh[2] = MFMA(a, w2, agh[2], 0, 0, 0);
            }
        }
    }

    // ---- phase B: gi = A2 @ W2^T (K=nK2*32) ----
    {
        const int nch  = (nK2 > 8) ? 2 : 1;
        const int klen = nK2 / nch;          // k-frags per chunk (dec 20, enc 8)
        const int uc   = klen * 4;           // 16B units per row per chunk
        const __bf16* wq0 = sW2 + ((size_t)t1 * nK2) * 512 + lane * 8;
        const __bf16* wq1 = sW2 + ((size_t)(t1 + 64) * nK2) * 512 + lane * 8;
        const __bf16* wq2 = sW2 + ((size_t)(t1 + 128) * nK2) * 512 + lane * 8;
        const int ar = (mg * 16 + r15) * uc;
        for (int ch = 0; ch < nch; ch++) {
            __syncthreads();   // protect previous contents
            if (src_t) {       // encoder: emb gather, 32 rows x 32 units
                for (int lin = tid; lin < 32 * 32; lin += 512) {
                    int r = lin >> 5, U = lin & 31;
                    int sv = src_t[m0 + r];
                    sv = (sv < 0) ? 0 : (sv > 63 ? 63 : sv);
                    uint4 v = *(const uint4*)(g_embs + sv * 256 + U * 8);
                    *(uint4*)(sBuf + (r * 32 + (U ^ (r & 7))) * 8) = v;
                }
            } else {           // decoder: Adec, 32 rows x 80 units per chunk
                for (int lin = tid; lin < 32 * 80; lin += 512) {
                    int r = lin / 80, U = lin - r * 80;
                    uint4 v = *(const uint4*)(g_Adec + (size_t)(m0 + r) * 1280 +
                                              (ch * 80 + U) * 8);
                    *(uint4*)(sBuf + (r * 80 + (U ^ (r & 7))) * 8) = v;
                }
            }
            __syncthreads();
#pragma unroll 4
            for (int cl = 0; cl < klen; cl++) {
                int c = ch * klen + cl;
                bfx8 a  = *(const bfx8*)(sBuf + (ar + ((cl * 4 + q) ^ xk)) * 8);
                bfx8 w0 = *(const bfx8*)(wq0 + c * 512);
                bfx8 w1 = *(const bfx8*)(wq1 + c * 512);
                bfx8 w2 = *(const bfx8*)(wq2 + c * 512);
                agi[0] = MFMA(a, w0, agi[0], 0, 0, 0);
                agi[1] = MFMA(a, w1, agi[1], 0, 0, 0);
                agi[2] = MFMA(a, w2, agi[2], 0, 0, 0);
            }
        }
    }

    // ---- GRU epilogue (wave owns its (jsub, mg) tile) ----
    const int jj = j0 + jsub * 16 + r15;
    const float bb1[3] = {b1[jj], b1[1024 + jj], b1[2048 + jj]};
    const float bb2[3] = {b2[jj], b2[1024 + jj], b2[2048 + jj]};
#pragma unroll
    for (int reg = 0; reg < 4; reg++) {
        int b_ = m0 + mg * 16 + q * 4 + reg;
        float gh0 = agh[0][reg] + bb1[0];
        float gh1 = agh[1][reg] + bb1[1];
        float gh2 = agh[2][reg] + bb1[2];
        float gi0 = agi[0][reg] + bb2[0];
        float gi1 = agi[1][reg] + bb2[1];
        float gi2 = agi[2][reg] + bb2[2];
        float r = 1.f / (1.f + __expf(-(gi0 + gh0)));
        float z = 1.f / (1.f + __expf(-(gi1 + gh1)));
        float n = fast_tanh(gi2 + r * gh2);
        size_t off = (size_t)b_ * 1024 + jj;
        float hv = (1.f - z) * n + z * g_h[off];
        g_h[off] = hv;
        hb_out[off] = (__bf16)hv;
        if (enc_t >= 0) g_enc_ops[(size_t)enc_t * 524288 + off] = (__bf16)hv;
    }
}

// ---------------------------------------------------------------------------
// enc_part = enc_ops @ W_attn[H:2H]^T, bf16 out. grid (16 n-tiles, 512 m).
// ---------------------------------------------------------------------------
__global__ __launch_bounds__(256) void k_ep()
{
    __shared__ __bf16 sA[32 * 1024];
    const int tid = threadIdx.x;
    const int w = tid >> 6, lane = tid & 63;
    const int r15 = lane & 15, q = lane >> 4;
    const int bx = blockIdx.x, m0 = blockIdx.y * 32;

#pragma unroll
    for (int i = 0; i < 16; i++) {
        int lin = tid + i * 256;
        int r = lin >> 7, U = lin & 127;
        uint4 v = *(const uint4*)(g_enc_ops + (size_t)(m0 + r) * 1024 + U * 8);
        *(uint4*)(sA + (r * 128 + (U ^ (r & 7))) * 8) = v;
    }
    __syncthreads();

    const int t = bx * 4 + w;
    const __bf16* wp = g_sWattnB + ((size_t)t * 32) * 512 + lane * 8;
    const int xk = r15 & 7;
    const int ar0 = r15 * 128, ar1 = (16 + r15) * 128;

    f32x4 acc[2];
    acc[0] = (f32x4){0.f, 0.f, 0.f, 0.f};
    acc[1] = (f32x4){0.f, 0.f, 0.f, 0.f};
#pragma unroll 4
    for (int c = 0; c < 32; c++) {
        int us = (c * 4 + q) ^ xk;
        bfx8 a0 = *(const bfx8*)(sA + (ar0 + us) * 8);
        bfx8 a1 = *(const bfx8*)(sA + (ar1 + us) * 8);
        bfx8 wv = *(const bfx8*)(wp + c * 512);
        acc[0] = MFMA(a0, wv, acc[0], 0, 0, 0);
        acc[1] = MFMA(a1, wv, acc[1], 0, 0, 0);
    }
    int n = bx * 64 + w * 16 + r15;
#pragma unroll
    for (int mf = 0; mf < 2; mf++)
#pragma unroll
        for (int reg = 0; reg < 4; reg++)
            g_enc_part[(size_t)(m0 + mf * 16 + q * 4 + reg) * 1024 + n] =
                (__bf16)acc[mf][reg];
}

// ---------------------------------------------------------------------------
// Fused [hpart | logits] from h (bf16). grid (18, 16).
// ---------------------------------------------------------------------------
__global__ __launch_bounds__(256) void k_hl(
    const __bf16* __restrict__ src, const float* __restrict__ battn,
    const float* __restrict__ bout, int lrow, float* __restrict__ outp)
{
    __shared__ __bf16 sA[32 * 1024];
    const int tid = threadIdx.x;
    const int w = tid >> 6, lane = tid & 63;
    const int r15 = lane & 15, q = lane >> 4;
    const int bx = blockIdx.x, m0 = blockIdx.y * 32;

#pragma unroll
    for (int i = 0; i < 16; i++) {
        int lin = tid + i * 256;
        int r = lin >> 7, U = lin & 127;
        uint4 v = *(const uint4*)(src + (size_t)(m0 + r) * 1024 + U * 8);
        *(uint4*)(sA + (r * 128 + (U ^ (r & 7))) * 8) = v;
    }
    __syncthreads();

    const __bf16* sW;
    int n;
    if (bx < 16) {
        sW = g_sWattnA;
        n = bx * 64 + w * 16 + r15;
    } else {
        if (lrow < 0) return;
        sW = g_sWout;
        n = (bx - 16) * 64 + w * 16 + r15;
    }
    const size_t tb = (size_t)((bx < 16 ? bx : bx - 16) * 4 + w);
    const __bf16* wp = sW + (tb * 32) * 512 + lane * 8;
    const int xk = r15 & 7;
    const int ar0 = r15 * 1024, ar1 = (16 + r15) * 1024;

    f32x4 acc[2];
    acc[0] = (f32x4){0.f, 0.f, 0.f, 0.f};
    acc[1] = (f32x4){0.f, 0.f, 0.f, 0.f};
#pragma unroll 4
    for (int c = 0; c < 32; c++) {
        int us = ((c * 4 + q) ^ xk) * 8;
        bfx8 a0 = *(const bfx8*)(sA + ar0 + us);
        bfx8 a1 = *(const bfx8*)(sA + ar1 + us);
        bfx8 wv = *(const bfx8*)(wp + c * 512);
        acc[0] = MFMA(a0, wv, acc[0], 0, 0, 0);
        acc[1] = MFMA(a1, wv, acc[1], 0, 0, 0);
    }

    if (bx < 16) {
        float bv = battn[n];
#pragma unroll
        for (int ms = 0; ms < 2; ms++)
#pragma unroll
            for (int reg = 0; reg < 4; reg++)
                g_hpart[(size_t)(m0 + ms * 16 + q * 4 + reg) * 1024 + n] =
                    acc[ms][reg] + bv;
    } else if (n < 70) {
        float bv = bout[n];
#pragma unroll
        for (int ms = 0; ms < 2; ms++)
#pragma unroll
            for (int reg = 0; reg < 4; reg++)
                outp[(size_t)lrow * 35840 +
                     (size_t)(m0 + ms * 16 + q * 4 + reg) * 70 + n] =
                    acc[ms][reg] + bv;
    }
}

// ---------------------------------------------------------------------------
// Attention step: x-select + embed + scores + softmax + alpha out + ctx.
// ---------------------------------------------------------------------------
__global__ __launch_bounds__(256) void k_attn(
    int j, const int* __restrict__ target, const int* __restrict__ tf,
    const float* __restrict__ v_attn, float* __restrict__ out)
{
    const int b = blockIdx.x, tid = threadIdx.x;
    const int lane = tid & 63, wave = tid >> 6;
    __shared__ float sc[32], sal[32];
    __shared__ int sx;
    if (wave == 0) {
        int xv;
        if (j == 0) xv = target[b];
        else if (*tf) xv = target[j * 512 + b];
        else {
            const float* row = out + (size_t)j * 35840 + b * 70;
            float bv = row[lane]; int bi = lane;
            if (lane < 6) {
                float v2 = row[lane + 64];
                if (v2 > bv) { bv = v2; bi = lane + 64; }
            }
#pragma unroll
            for (int off = 32; off; off >>= 1) {
                float ov = __shfl_down(bv, off);
                int   oi = __shfl_down(bi, off);
                if (ov > bv || (ov == bv && oi < bi)) { bv = ov; bi = oi; }
            }
            xv = bi;
        }
        if (lane == 0) sx = (xv < 0) ? 0 : (xv > 69 ? 69 : xv);
    }
    float hpv[16], vsv[16];
    {
        const float* hp = g_hpart + (size_t)b * 1024;
#pragma unroll
        for (int u = 0; u < 8; u++) {
            hpv[u]     = hp[lane * 8 + u];
            hpv[8 + u] = hp[512 + lane * 8 + u];
            vsv[u]     = v_attn[lane * 8 + u];
            vsv[8 + u] = v_attn[512 + lane * 8 + u];
        }
    }
    __syncthreads();
    g_Adec[(size_t)b * 1280 + 1024 + tid] = g_embt[sx * 256 + tid];
    for (int s = wave * 8; s < wave * 8 + 8; s++) {
        const __bf16* ep = g_enc_part + ((size_t)s * 512 + b) * 1024;
        bfx8 e0 = *(const bfx8*)(ep + lane * 8);
        bfx8 e1 = *(const bfx8*)(ep + 512 + lane * 8);
        float part = 0.f;
#pragma unroll
        for (int u = 0; u < 8; u++) {
            part += vsv[u]     * fast_tanh((float)e0[u] + hpv[u]);
            part += vsv[8 + u] * fast_tanh((float)e1[u] + hpv[8 + u]);
        }
#pragma unroll
        for (int off = 32; off; off >>= 1) part += __shfl_down(part, off);
        if (lane == 0) sc[s] = part;
    }
    __syncthreads();
    float mx = sc[0];
#pragma unroll
    for (int s = 1; s < 32; s++) mx = fmaxf(mx, sc[s]);
    float den = 0.f;
#pragma unroll
    for (int s = 0; s < 32; s++) den += __expf(sc[s] - mx);
    float rden = 1.f / den;
    if (tid < 32) {
        float al = __expf(sc[tid] - mx) * rden;
        sal[tid] = al;
        out[1146880 + (size_t)j * 16384 + b * 32 + tid] = al;
    }
    __syncthreads();
    float c0 = 0, c1 = 0, c2 = 0, c3 = 0;
    const __bf16* eo = g_enc_ops + (size_t)b * 1024 + tid * 4;
#pragma unroll 4
    for (int s = 0; s < 32; s++) {
        bfx4 e = *(const bfx4*)(eo + (size_t)s * 524288);
        float al = sal[s];
        c0 += al * (float)e[0]; c1 += al * (float)e[1];
        c2 += al * (float)e[2]; c3 += al * (float)e[3];
    }
    bfx4 o = {(__bf16)c0, (__bf16)c1, (__bf16)c2, (__bf16)c3};
    *(bfx4*)(&g_Adec[(size_t)b * 1280 + tid * 4]) = o;
}

// ---------------------------------------------------------------------------
extern "C" void kernel_launch(void* const* d_in, const int* in_sizes, int n_in,
                              void* d_out, int out_size, void* d_ws, size_t ws_size,
                              hipStream_t stream)
{
    const int*   source   = (const int*)d_in[0];
    const int*   target   = (const int*)d_in[1];
    const int*   tf       = (const int*)d_in[2];
    const float* emb_src  = (const float*)d_in[3];
    const float* W_ih_enc = (const float*)d_in[4];
    const float* W_hh_enc = (const float*)d_in[5];
    const float* b_ih_enc = (const float*)d_in[6];
    const float* b_hh_enc = (const float*)d_in[7];
    const float* emb_tgt  = (const float*)d_in[8];
    const float* W_attn   = (const float*)d_in[9];
    const float* b_attn   = (const float*)d_in[10];
    const float* v_attn   = (const float*)d_in[11];
    const float* W_ih_dec = (const float*)d_in[12];
    const float* W_hh_dec = (const float*)d_in[13];
    const float* b_ih_dec = (const float*)d_in[14];
    const float* b_hh_dec = (const float*)d_in[15];
    const float* W_out    = (const float*)d_in[16];
    const float* b_out    = (const float*)d_in[17];
    float* out = (float*)d_out;

    void *p_hb, *p_sWhhe, *p_sWihe, *p_sWhhd, *p_sWihd, *p_sWattnA, *p_sWattnB,
         *p_sWout, *p_embs, *p_embt;
    hipGetSymbolAddress(&p_hb,      HIP_SYMBOL(g_hb));
    hipGetSymbolAddress(&p_sWhhe,   HIP_SYMBOL(g_sWhhe));
    hipGetSymbolAddress(&p_sWihe,   HIP_SYMBOL(g_sWihe));
    hipGetSymbolAddress(&p_sWhhd,   HIP_SYMBOL(g_sWhhd));
    hipGetSymbolAddress(&p_sWihd,   HIP_SYMBOL(g_sWihd));
    hipGetSymbolAddress(&p_sWattnA, HIP_SYMBOL(g_sWattnA));
    hipGetSymbolAddress(&p_sWattnB, HIP_SYMBOL(g_sWattnB));
    hipGetSymbolAddress(&p_sWout,   HIP_SYMBOL(g_sWout));
    hipGetSymbolAddress(&p_embs,    HIP_SYMBOL(g_embs));
    hipGetSymbolAddress(&p_embt,    HIP_SYMBOL(g_embt));
    __bf16* hb0 = (__bf16*)p_hb;
    __bf16* hb1 = hb0 + 512 * 1024;

    // ---- one-time setup ----
    k_cvt<<<16, 256, 0, stream>>>(emb_src, (__bf16*)p_embs, 64 * 256 / 4);
    k_cvt<<<18, 256, 0, stream>>>(emb_tgt, (__bf16*)p_embt, 70 * 256 / 4);
    swz_rm<<<1536, 256, 0, stream>>>(W_hh_enc, (__bf16*)p_sWhhe, 32, 393216);
    swz_rm<<<384,  256, 0, stream>>>(W_ih_enc, (__bf16*)p_sWihe, 8,  98304);
    swz_rm<<<1536, 256, 0, stream>>>(W_hh_dec, (__bf16*)p_sWhhd, 32, 393216);
    swz_rm<<<1920, 256, 0, stream>>>(W_ih_dec, (__bf16*)p_sWihd, 40, 491520);
    swz_cm<<<512,  256, 0, stream>>>(W_attn, (__bf16*)p_sWattnA, 32, 1024, 1024, 131072);
    swz_cm<<<512,  256, 0, stream>>>(W_attn + (size_t)1024 * 1024,
                                     (__bf16*)p_sWattnB, 32, 1024, 1024, 131072);
    swz_cm<<<64,   256, 0, stream>>>(W_out, (__bf16*)p_sWout, 32, 70, 70, 16384);
    k_init<<<2048, 256, 0, stream>>>(out);

    // -------- Encoder: 32 steps --------
    for (int t = 0; t < 32; t++) {
        __bf16* hin  = (t & 1) ? hb1 : hb0;
        __bf16* hout = (t & 1) ? hb0 : hb1;
        gru_step<<<dim3(16, 16), 512, 0, stream>>>(
            hin, hout, (__bf16*)p_sWhhe, b_hh_enc,
            (__bf16*)p_sWihe, b_ih_enc, 8, source + t * 512, t);
    }
    // h_enc lands in hb0

    // enc_part = enc_ops @ W_attn[H:2H]^T
    k_ep<<<dim3(16, 512), 256, 0, stream>>>();

    // hpart for step 0
    k_hl<<<dim3(18, 16), 256, 0, stream>>>(hb0, b_attn, b_out, -1, out);

    // -------- Decoder: 31 steps --------
    for (int j = 0; j < 31; j++) {
        __bf16* hin  = (j & 1) ? hb1 : hb0;
        __bf16* hout = (j & 1) ? hb0 : hb1;
        k_attn<<<512, 256, 0, stream>>>(j, target, tf, v_attn, out);
        gru_step<<<dim3(16, 16), 512, 0, stream>>>(
            hin, hout, (__bf16*)p_sWhhd, b_hh_dec,
            (__bf16*)p_sWihd, b_ih_dec, 40, nullptr, -1);
        k_hl<<<dim3(18, 16), 256, 0, stream>>>(hout, b_attn, b_out, j + 1, out);
    }
}